// Round 9
// baseline (248.903 us; speedup 1.0000x reference)
//
#include <hip/hip_runtime.h>
#include <hip/hip_bf16.h>
#include <math.h>

#define B_SZ 4
#define T_SZ 2048
#define C_SZ 512
#define H_SZ 8
#define HD 64
#define QSCALE 0.1803368801111137f  /* log2(e)/8 : folds 1/sqrt(64) and exp->exp2 */

typedef __bf16 bf16;
typedef __bf16 bf16x8 __attribute__((ext_vector_type(8)));
typedef float f32x4 __attribute__((ext_vector_type(4)));

__device__ __forceinline__ f32x4 mfma16(bf16x8 a, bf16x8 b, f32x4 c) {
    return __builtin_amdgcn_mfma_f32_16x16x32_bf16(a, b, c, 0, 0, 0);
}

#define GLD_LDS16(g, l) __builtin_amdgcn_global_load_lds( \
    (__attribute__((address_space(1))) void*)(void*)(g),  \
    (__attribute__((address_space(3))) void*)(l), 16, 0, 0)

// ---------------------------------------------------------------- convert
__global__ __launch_bounds__(256) void cvt_all(
    const float* __restrict__ x, const float* __restrict__ wqkv,
    const float* __restrict__ wout, bf16* __restrict__ xb,
    bf16* __restrict__ wqb, bf16* __restrict__ wob) {
  int i = blockIdx.x * 256 + threadIdx.x;
  const int n0 = (B_SZ*T_SZ*C_SZ)/4, n1 = (3*C_SZ*C_SZ)/4, n2 = (C_SZ*C_SZ)/4;
  const float4* s; bf16* d; int j;
  if (i < n0)                { s = (const float4*)x;    d = xb;  j = i; }
  else if (i < n0 + n1)      { s = (const float4*)wqkv; d = wqb; j = i - n0; }
  else if (i < n0 + n1 + n2) { s = (const float4*)wout; d = wob; j = i - n0 - n1; }
  else return;
  float4 v = s[j];
  union { bf16 h[4]; uint2 u; } p;
  p.h[0] = (bf16)v.x; p.h[1] = (bf16)v.y; p.h[2] = (bf16)v.z; p.h[3] = (bf16)v.w;
  *(uint2*)(d + (size_t)j * 4) = p.u;
}

// ---------------------------------------------------------------- GEMM1: x @ Wqkv^T, RoPE fused
__global__ __launch_bounds__(256) void gemm_qkv(
    const bf16* __restrict__ A, const bf16* __restrict__ Bw,
    const float* __restrict__ cp, const float* __restrict__ sp,
    bf16* __restrict__ oq, bf16* __restrict__ ok, bf16* __restrict__ ov) {
  __shared__ bf16 sA[128 * 32];
  __shared__ bf16 sB[128 * 32];
  const int tid = threadIdx.x;
  const int m0 = blockIdx.x * 128, n0 = blockIdx.y * 128;
  const int w = tid >> 6, lane = tid & 63, quad = lane >> 4, l16 = lane & 15;
  const int wm = (w >> 1) * 64, wn = (w & 1) * 64;
  const int srow = tid >> 2, scol = (tid & 3) * 8;
  const int K = C_SZ;
  f32x4 acc[4][4] = {};
  for (int k0 = 0; k0 < K; k0 += 32) {
    __syncthreads();
    const bf16* ga = A  + (size_t)(m0 + srow) * K + k0 + scol;
    const bf16* gb = Bw + (size_t)(n0 + srow) * K + k0 + scol;
    GLD_LDS16(ga,                 sA + tid * 8);
    GLD_LDS16(ga + (size_t)64*K,  sA + tid * 8 + 2048);
    GLD_LDS16(gb,                 sB + tid * 8);
    GLD_LDS16(gb + (size_t)64*K,  sB + tid * 8 + 2048);
    __syncthreads();
    bf16x8 af[4], bfr[4];
#pragma unroll
    for (int i = 0; i < 4; i++)
      af[i] = *(const bf16x8*)(sA + (wm + i*16 + l16) * 32 + quad * 8);
#pragma unroll
    for (int j = 0; j < 4; j++)
      bfr[j] = *(const bf16x8*)(sB + (wn + j*16 + l16) * 32 + quad * 8);
#pragma unroll
    for (int i = 0; i < 4; i++)
#pragma unroll
      for (int j = 0; j < 4; j++)
        acc[i][j] = mfma16(af[i], bfr[j], acc[i][j]);
  }
  const int three = n0 >> 9;  // 0=q,1=k,2=v (uniform per block)
  if (three < 2) {
    bf16* dst0 = three == 0 ? oq : ok;
#pragma unroll
    for (int i = 0; i < 4; i++)
#pragma unroll
      for (int r = 0; r < 4; r++) {
        const int m = m0 + wm + i*16 + quad*4 + r;
        const int b = m >> 11, t = m & (T_SZ - 1);
#pragma unroll
        for (int j = 0; j < 2; j++) {
          const int dcol = j*16 + l16;                  // < 32
          const int h = ((n0 & 511) + wn + dcol) >> 6;
          const float c1 = cp[t*HD + dcol],     s1 = sp[t*HD + dcol];
          const float c2 = cp[t*HD + dcol + 32], s2 = sp[t*HD + dcol + 32];
          const float a = acc[i][j][r], bb = acc[i][j+2][r];
          float o1 = a * c1 - bb * s1;
          float o2 = bb * c2 + a * s2;
          if (three == 0) { o1 *= QSCALE; o2 *= QSCALE; }
          bf16* dst = dst0 + (((size_t)(b*H_SZ + h)) * T_SZ + t) * HD;
          dst[dcol]      = (bf16)o1;
          dst[dcol + 32] = (bf16)o2;
        }
      }
  } else {
#pragma unroll
    for (int i = 0; i < 4; i++)
#pragma unroll
      for (int j = 0; j < 4; j++) {
        const int n = n0 + wn + j*16 + l16;
        const int h = (n & 511) >> 6, dcol = n & 63;
#pragma unroll
        for (int r = 0; r < 4; r++) {
          const int m = m0 + wm + i*16 + quad*4 + r;
          const int b = m >> 11, t = m & (T_SZ - 1);
          ov[(((size_t)(b*H_SZ + h)) * HD + dcol) * T_SZ + t] = (bf16)acc[i][j][r];
        }
      }
  }
}

// ---------------------------------------------------------------- GEMM2: ao @ Wout^T -> fp32
__global__ __launch_bounds__(256) void gemm_out(
    const bf16* __restrict__ A, const bf16* __restrict__ Bw,
    float* __restrict__ dst) {
  __shared__ bf16 sA[64 * 32];
  __shared__ bf16 sB[128 * 32];
  const int tid = threadIdx.x;
  const int m0 = blockIdx.x * 64, n0 = blockIdx.y * 128;
  const int w = tid >> 6, lane = tid & 63, quad = lane >> 4, l16 = lane & 15;
  const int wm = (w & 1) * 32, wn = (w >> 1) * 64;
  const int srow = tid >> 2, scol = (tid & 3) * 8;
  const int K = C_SZ;
  f32x4 acc[2][4] = {};
  for (int k0 = 0; k0 < K; k0 += 32) {
    __syncthreads();
    const bf16* ga = A  + (size_t)(m0 + srow) * K + k0 + scol;
    const bf16* gb = Bw + (size_t)(n0 + srow) * K + k0 + scol;
    GLD_LDS16(ga,                 sA + tid * 8);
    GLD_LDS16(gb,                 sB + tid * 8);
    GLD_LDS16(gb + (size_t)64*K,  sB + tid * 8 + 2048);
    __syncthreads();
    bf16x8 af[2], bfr[4];
#pragma unroll
    for (int i = 0; i < 2; i++)
      af[i] = *(const bf16x8*)(sA + (wm + i*16 + l16) * 32 + quad * 8);
#pragma unroll
    for (int j = 0; j < 4; j++)
      bfr[j] = *(const bf16x8*)(sB + (wn + j*16 + l16) * 32 + quad * 8);
#pragma unroll
    for (int i = 0; i < 2; i++)
#pragma unroll
      for (int j = 0; j < 4; j++)
        acc[i][j] = mfma16(af[i], bfr[j], acc[i][j]);
  }
#pragma unroll
  for (int i = 0; i < 2; i++)
#pragma unroll
    for (int j = 0; j < 4; j++)
#pragma unroll
      for (int r = 0; r < 4; r++) {
        const int m = m0 + wm + i*16 + quad*4 + r;
        const int n = n0 + wn + j*16 + l16;
        dst[(size_t)m * C_SZ + n] = acc[i][j][r];
      }
}

// ---------------------------------------------------------------- flash attention v3b
// Same inner loop as the measured-best 43us version (KT=32, 64q/wave, dbuf
// K/V^T staging, wave-private P round-trip), but re-segmented for 4 blocks/CU:
// per bh, 288 K-iters over 8 q-tiles (tile qi has 8(qi+1) iters, g0=4qi(qi+1)),
// split into 32 segments of 9 -> 1024 uniform blocks. LDS 36 KB x 4 = 144 <=
// 160 KB; __launch_bounds__(256,4) caps VGPR at 128 (was 84) so 16 waves/CU.
// Un-normalized partials (O bf16 32KB, l fp32); <=8 contributors/tile.
__device__ __forceinline__ int tile_of(int g) {
  int qi = (int)((sqrtf((float)g + 1.f) - 1.f) * 0.5f);
  while (4 * (qi + 1) * (qi + 2) <= g) ++qi;
  while (4 * qi * (qi + 1) > g) --qi;
  return qi;
}

__global__ __launch_bounds__(256, 4) void flash_attn(
    const bf16* __restrict__ qb, const bf16* __restrict__ kb,
    const bf16* __restrict__ vtb, bf16* __restrict__ Oa,
    float* __restrict__ lbuf) {
  __shared__ bf16 sK[2][32 * 64];   // K tile: 32 k-rows x 64 d
  __shared__ bf16 sVT[2][64 * 32];  // V^T tile: 64 d-rows x 32 t
  __shared__ bf16 sP[4][2560];      // per wave: P^T 64 q-rows x pitch 40
  const int tid = threadIdx.x, w = tid >> 6, lane = tid & 63;
  const int quad = lane >> 4, l16 = lane & 15;
  const int bh = blockIdx.x & 31;          // idx%8 == bh%8 -> XCD affinity
  const int p  = blockIdx.x >> 5;          // 0..31
  const int gs = 9 * p, ge = gs + 9;
  int qi = tile_of(gs);
  int tend = 4 * (qi + 1) * (qi + 2);
  int q0w = qi * 256 + w * 64;
  const bf16* Q  = qb  + (size_t)bh * T_SZ * HD;
  const bf16* Kp = kb  + (size_t)bh * T_SZ * HD;
  const bf16* Vt = vtb + (size_t)bh * HD * T_SZ;
  bf16x8 qf[4][2];
#pragma unroll
  for (int nt = 0; nt < 4; nt++)
#pragma unroll
    for (int ds = 0; ds < 2; ds++)
      qf[nt][ds] = *(const bf16x8*)(Q + (size_t)(q0w + nt*16 + l16) * HD + ds*32 + quad*8);
  float l_[4] = {0.f, 0.f, 0.f, 0.f};
  f32x4 ot[4][4] = {};
  bf16* sPw = &sP[w][0];
  const int srow = tid >> 3, scg = (tid & 7) ^ (srow & 7);   // K staging
  const int vrow = tid >> 2, vcg = (tid & 3) ^ (vrow & 3);   // V^T staging

  // emit un-normalized partial (O rows bf16 + per-row l fp32) for tile qi
  auto partial_epilogue = [&]() {
    const int pf = (4 * qi * (qi + 1)) / 9;      // first block of tile qi
    const int rec = (bh * 8 + qi) * 8 + (p - pf);
#pragma unroll
    for (int nt = 0; nt < 4; nt++) {
      float s = l_[nt];
      s += __shfl_xor(s, 16);
      s += __shfl_xor(s, 32);
      if (quad == 0) lbuf[rec * 256 + w*64 + nt*16 + l16] = s;
    }
    // two halves of 32 q-rows via per-wave LDS scratch (pitch 72)
#pragma unroll
    for (int h = 0; h < 2; h++) {
      asm volatile("" ::: "memory");
#pragma unroll
      for (int dt = 0; dt < 4; dt++)
#pragma unroll
        for (int n2 = 0; n2 < 2; n2++) {
          const int nt = h*2 + n2;
          union { bf16 h4[4]; unsigned long long ull; } pk;
#pragma unroll
          for (int r = 0; r < 4; r++) pk.h4[r] = (bf16)ot[dt][nt][r];
          *(unsigned long long*)(sPw + (n2*16 + l16)*72 + dt*16 + quad*4) = pk.ull;
        }
      asm volatile("" ::: "memory");
      const int oq = lane >> 1, hf = lane & 1;
      bf16* dst = Oa + (size_t)rec * 16384 + (w*64 + h*32 + oq) * 64 + hf * 32;
#pragma unroll
      for (int j = 0; j < 4; j++)
        *(uint4*)(dst + j*8) = *(const uint4*)(sPw + oq*72 + hf*32 + j*8);
    }
    asm volatile("" ::: "memory");
  };

  // stage first iter into buf[gs&1]
  {
    const int kt0 = (gs - 4*qi*(qi+1)) * 32;
    GLD_LDS16(Kp + (size_t)(kt0 + srow) * HD + scg*8, sK[gs & 1]  + tid*8);
    GLD_LDS16(Vt + (size_t)vrow * T_SZ + kt0 + vcg*8, sVT[gs & 1] + tid*8);
  }

  for (int g = gs; g < ge; g++) {
    const int kt = (g - 4*qi*(qi+1)) * 32;
    __syncthreads();        // drains staging of buf[g&1]; fences prev compute
    if (g + 1 < ge) {       // prefetch next iter into the other buffer
      const int qn = (g + 1 >= tend) ? qi + 1 : qi;
      const int kn = (g + 1 - 4*qn*(qn+1)) * 32;
      GLD_LDS16(Kp + (size_t)(kn + srow) * HD + scg*8, sK[(g+1) & 1]  + tid*8);
      GLD_LDS16(Vt + (size_t)vrow * T_SZ + kn + vcg*8, sVT[(g+1) & 1] + tid*8);
    }
    if (kt <= q0w + 63) {   // not fully masked for this wave
      const bf16* cK = sK[g & 1];
      const bf16* cV = sVT[g & 1];
      // ---- S^T = K.Q^T : st[mt][nt], m=k-pos (32), n=q-pos (64)
      f32x4 st[2][4] = {};
#pragma unroll
      for (int mt = 0; mt < 2; mt++) {
#pragma unroll
        for (int ds = 0; ds < 2; ds++) {
          const int row = mt*16 + l16, cl = ds*4 + quad;
          const bf16x8 kf = *(const bf16x8*)(cK + row*64 + (cl ^ (row & 7)) * 8);
#pragma unroll
          for (int nt = 0; nt < 4; nt++)
            st[mt][nt] = mfma16(kf, qf[nt][ds], st[mt][nt]);
        }
      }
      // ---- causal mask (diagonal tiles only), exp2, pack P^T, partial sums
      if (kt + 31 > q0w) {
#pragma unroll
        for (int nt = 0; nt < 4; nt++) {
          const int qg = q0w + nt*16 + l16;
          const int kb0 = kt + quad*4;
#pragma unroll
          for (int mt = 0; mt < 2; mt++)
#pragma unroll
            for (int r = 0; r < 4; r++)
              st[mt][nt][r] = (kb0 + mt*16 + r <= qg) ? st[mt][nt][r] : -1e30f;
        }
      }
#pragma unroll
      for (int nt = 0; nt < 4; nt++) {
        float sum = 0.f;
#pragma unroll
        for (int mt = 0; mt < 2; mt++) {
          union { bf16 h4[4]; unsigned long long ull; } pk;
#pragma unroll
          for (int r = 0; r < 4; r++) {
            const float pv = __builtin_amdgcn_exp2f(st[mt][nt][r]);
            sum += pv;
            pk.h4[r] = (bf16)pv;
          }
          *(unsigned long long*)(sPw + (nt*16 + l16)*40 + mt*16 + quad*4) = pk.ull;
        }
        l_[nt] += sum;
      }
      asm volatile("" ::: "memory");   // wave-local: keep P writes before reads
      // ---- O^T += V^T . P  : m=d (64), n=q (64), k=t (32)
      bf16x8 pfr[4];
#pragma unroll
      for (int nt = 0; nt < 4; nt++)
        pfr[nt] = *(const bf16x8*)(sPw + (nt*16 + l16)*40 + quad*8);
#pragma unroll
      for (int dt = 0; dt < 4; dt++) {
        const int row = dt*16 + l16;
        const bf16x8 vf = *(const bf16x8*)(cV + row*32 + (quad ^ (row & 3)) * 8);
#pragma unroll
        for (int nt = 0; nt < 4; nt++)
          ot[dt][nt] = mfma16(vf, pfr[nt], ot[dt][nt]);
      }
    }
    if (g + 1 == tend || g + 1 == ge) {   // end of tile segment: emit partial
      partial_epilogue();
      if (g + 1 == tend && g + 1 < ge) {  // advance to next tile
        qi++; tend = 4 * (qi + 1) * (qi + 2); q0w = qi * 256 + w * 64;
#pragma unroll
        for (int nt = 0; nt < 4; nt++)
#pragma unroll
          for (int ds = 0; ds < 2; ds++)
            qf[nt][ds] = *(const bf16x8*)(Q + (size_t)(q0w + nt*16 + l16) * HD + ds*32 + quad*8);
#pragma unroll
        for (int nt = 0; nt < 4; nt++) l_[nt] = 0.f;
#pragma unroll
        for (int dt = 0; dt < 4; dt++)
#pragma unroll
          for (int nt = 0; nt < 4; nt++)
            ot[dt][nt] = f32x4{0.f, 0.f, 0.f, 0.f};
      }
    }
  }
}

// ---------------------------------------------------------------- combine partials
__global__ __launch_bounds__(256) void combine_o(
    const bf16* __restrict__ Oa, const float* __restrict__ lbuf,
    bf16* __restrict__ ao) {
  const int inst = blockIdx.x;           // 256 = 8 qi x 32 bh
  const int bh = inst & 31, qi = inst >> 5;
  const int b = bh >> 3, h = bh & 7;
  const int g0 = 4 * qi * (qi + 1), gL = g0 + 8*qi + 7;
  const int pf = g0 / 9, pl = gL / 9;
  const int n = pl - pf + 1;             // contributors (1..8)
  const int base = (bh * 8 + qi) * 8;
  const int q = threadIdx.x;             // 0..255
  float l = 0.f;
  for (int s = 0; s < n; s++) l += lbuf[(base + s) * 256 + q];
  const float inv = 1.f / l;
  float acc[64] = {};
  for (int s = 0; s < n; s++) {
    const bf16* ps = Oa + ((size_t)(base + s)) * 16384 + q * 64;
#pragma unroll
    for (int c = 0; c < 8; c++) {
      union { uint4 u; bf16 h8[8]; } a;
      a.u = *(const uint4*)(ps + c*8);
#pragma unroll
      for (int j = 0; j < 8; j++) acc[c*8 + j] += (float)a.h8[j];
    }
  }
  const int tg = qi * 256 + q;
  bf16* dst = ao + ((size_t)(b*T_SZ + tg)) * C_SZ + h*HD;
#pragma unroll
  for (int c = 0; c < 8; c++) {
    union { uint4 u; bf16 h8[8]; } o;
#pragma unroll
    for (int j = 0; j < 8; j++) o.h8[j] = (bf16)(acc[c*8 + j] * inv);
    *(uint4*)(dst + c*8) = o.u;
  }
}

// ---------------------------------------------------------------- launch
extern "C" void kernel_launch(void* const* d_in, const int* in_sizes, int n_in,
                              void* d_out, int out_size, void* d_ws, size_t ws_size,
                              hipStream_t stream) {
  const float* x    = (const float*)d_in[0];
  const float* cosp = (const float*)d_in[1];
  const float* sinp = (const float*)d_in[2];
  const float* wqkv = (const float*)d_in[3];
  const float* wout = (const float*)d_in[4];
  char* ws = (char*)d_ws;
  bf16* xb    = (bf16*)(ws);                 //  8,388,608
  bf16* wqkvb = (bf16*)(ws +  8388608);      //  1,572,864
  bf16* woutb = (bf16*)(ws +  9961472);      //    524,288
  bf16* qbuf  = (bf16*)(ws + 10485760);      //  8,388,608  (B,H,T,hd)
  bf16* kbuf  = (bf16*)(ws + 18874368);      //  8,388,608  (B,H,T,hd)
  bf16* vtbuf = (bf16*)(ws + 27262976);      //  8,388,608  (B,H,hd,T)
  bf16* ao    = (bf16*)(ws + 35651584);      //  8,388,608  (B,T,C)
  bf16* Oa    = (bf16*)(ws + 44040192);      // 67,108,864  2048 recs x 32 KB
  float* lbuf = (float*)(ws + 111149056);    //  2,097,152

  cvt_all<<<dim3(5120), dim3(256), 0, stream>>>(x, wqkv, wout, xb, wqkvb, woutb);
  gemm_qkv<<<dim3(64, 12), dim3(256), 0, stream>>>(
      xb, wqkvb, cosp, sinp, qbuf, kbuf, vtbuf);
  flash_attn<<<dim3(1024), dim3(256), 0, stream>>>(qbuf, kbuf, vtbuf, Oa, lbuf);
  combine_o<<<dim3(256), dim3(256), 0, stream>>>(Oa, lbuf, ao);
  gemm_out<<<dim3(128, 4), dim3(256), 0, stream>>>(ao, woutb, (float*)d_out);
}

// Round 10
// 150.511 us; speedup vs baseline: 1.6537x; 1.6537x over previous
//
#include <hip/hip_runtime.h>
#include <hip/hip_bf16.h>
#include <math.h>

#define B_SZ 4
#define T_SZ 2048
#define C_SZ 512
#define H_SZ 8
#define HD 64
#define QSCALE 0.1803368801111137f  /* log2(e)/8 : folds 1/sqrt(64) and exp->exp2 */

typedef __bf16 bf16;
typedef __bf16 bf16x8 __attribute__((ext_vector_type(8)));
typedef float f32x4 __attribute__((ext_vector_type(4)));

__device__ __forceinline__ f32x4 mfma16(bf16x8 a, bf16x8 b, f32x4 c) {
    return __builtin_amdgcn_mfma_f32_16x16x32_bf16(a, b, c, 0, 0, 0);
}

#define GLD_LDS16(g, l) __builtin_amdgcn_global_load_lds( \
    (__attribute__((address_space(1))) void*)(void*)(g),  \
    (__attribute__((address_space(3))) void*)(l), 16, 0, 0)

// ---------------------------------------------------------------- convert
__global__ __launch_bounds__(256) void cvt_all(
    const float* __restrict__ x, const float* __restrict__ wqkv,
    const float* __restrict__ wout, bf16* __restrict__ xb,
    bf16* __restrict__ wqb, bf16* __restrict__ wob) {
  int i = blockIdx.x * 256 + threadIdx.x;
  const int n0 = (B_SZ*T_SZ*C_SZ)/4, n1 = (3*C_SZ*C_SZ)/4, n2 = (C_SZ*C_SZ)/4;
  const float4* s; bf16* d; int j;
  if (i < n0)                { s = (const float4*)x;    d = xb;  j = i; }
  else if (i < n0 + n1)      { s = (const float4*)wqkv; d = wqb; j = i - n0; }
  else if (i < n0 + n1 + n2) { s = (const float4*)wout; d = wob; j = i - n0 - n1; }
  else return;
  float4 v = s[j];
  union { bf16 h[4]; uint2 u; } p;
  p.h[0] = (bf16)v.x; p.h[1] = (bf16)v.y; p.h[2] = (bf16)v.z; p.h[3] = (bf16)v.w;
  *(uint2*)(d + (size_t)j * 4) = p.u;
}

// ---------------------------------------------------------------- GEMM1: x @ Wqkv^T, RoPE fused
// C[m,n] = sum_k A[m,k]*Bw[n,k]. 128x128 tile, BK=32. Epilogue: q/k get RoPE
// (pairs (d,d+32) = acc[i][j], acc[i][j+2] in the same lane), q also *QSCALE;
// q,k -> (B,H,T,hd); v -> transposed (B,H,hd,T) with r-quad packed b64 stores
// (4 consecutive t per store -- contiguous in the (d,t) layout).
__global__ __launch_bounds__(256) void gemm_qkv(
    const bf16* __restrict__ A, const bf16* __restrict__ Bw,
    const float* __restrict__ cp, const float* __restrict__ sp,
    bf16* __restrict__ oq, bf16* __restrict__ ok, bf16* __restrict__ ov) {
  __shared__ bf16 sA[128 * 32];
  __shared__ bf16 sB[128 * 32];
  const int tid = threadIdx.x;
  const int m0 = blockIdx.x * 128, n0 = blockIdx.y * 128;
  const int w = tid >> 6, lane = tid & 63, quad = lane >> 4, l16 = lane & 15;
  const int wm = (w >> 1) * 64, wn = (w & 1) * 64;
  const int srow = tid >> 2, scol = (tid & 3) * 8;
  const int K = C_SZ;
  f32x4 acc[4][4] = {};
  for (int k0 = 0; k0 < K; k0 += 32) {
    __syncthreads();
    const bf16* ga = A  + (size_t)(m0 + srow) * K + k0 + scol;
    const bf16* gb = Bw + (size_t)(n0 + srow) * K + k0 + scol;
    GLD_LDS16(ga,                 sA + tid * 8);
    GLD_LDS16(ga + (size_t)64*K,  sA + tid * 8 + 2048);
    GLD_LDS16(gb,                 sB + tid * 8);
    GLD_LDS16(gb + (size_t)64*K,  sB + tid * 8 + 2048);
    __syncthreads();
    bf16x8 af[4], bfr[4];
#pragma unroll
    for (int i = 0; i < 4; i++)
      af[i] = *(const bf16x8*)(sA + (wm + i*16 + l16) * 32 + quad * 8);
#pragma unroll
    for (int j = 0; j < 4; j++)
      bfr[j] = *(const bf16x8*)(sB + (wn + j*16 + l16) * 32 + quad * 8);
#pragma unroll
    for (int i = 0; i < 4; i++)
#pragma unroll
      for (int j = 0; j < 4; j++)
        acc[i][j] = mfma16(af[i], bfr[j], acc[i][j]);
  }
  const int three = n0 >> 9;  // 0=q,1=k,2=v (uniform per block)
  if (three < 2) {
    bf16* dst0 = three == 0 ? oq : ok;
#pragma unroll
    for (int i = 0; i < 4; i++)
#pragma unroll
      for (int r = 0; r < 4; r++) {
        const int m = m0 + wm + i*16 + quad*4 + r;
        const int b = m >> 11, t = m & (T_SZ - 1);
#pragma unroll
        for (int j = 0; j < 2; j++) {
          const int dcol = j*16 + l16;                  // < 32
          const int h = ((n0 & 511) + wn + dcol) >> 6;
          const float c1 = cp[t*HD + dcol],     s1 = sp[t*HD + dcol];
          const float c2 = cp[t*HD + dcol + 32], s2 = sp[t*HD + dcol + 32];
          const float a = acc[i][j][r], bb = acc[i][j+2][r];
          float o1 = a * c1 - bb * s1;
          float o2 = bb * c2 + a * s2;
          if (three == 0) { o1 *= QSCALE; o2 *= QSCALE; }
          bf16* dst = dst0 + (((size_t)(b*H_SZ + h)) * T_SZ + t) * HD;
          dst[dcol]      = (bf16)o1;
          dst[dcol + 32] = (bf16)o2;
        }
      }
  } else {
#pragma unroll
    for (int i = 0; i < 4; i++)
#pragma unroll
      for (int j = 0; j < 4; j++) {
        const int n = n0 + wn + j*16 + l16;
        const int h = (n & 511) >> 6, dcol = n & 63;
        const int m = m0 + wm + i*16 + quad*4;   // r = 0..3 -> t, t+1, t+2, t+3
        const int b = m >> 11, t = m & (T_SZ - 1);
        union { bf16 h4[4]; unsigned long long ull; } pk;
#pragma unroll
        for (int r = 0; r < 4; r++) pk.h4[r] = (bf16)acc[i][j][r];
        *(unsigned long long*)(ov + (((size_t)(b*H_SZ + h)) * HD + dcol) * T_SZ + t) = pk.ull;
      }
  }
}

// ---------------------------------------------------------------- GEMM2: ao @ Wout^T -> fp32
// 64x128 tile -> grid 128x4 = 512 blocks (2/CU). Wave: 32x64 (acc[2][4]).
__global__ __launch_bounds__(256) void gemm_out(
    const bf16* __restrict__ A, const bf16* __restrict__ Bw,
    float* __restrict__ dst) {
  __shared__ bf16 sA[64 * 32];
  __shared__ bf16 sB[128 * 32];
  const int tid = threadIdx.x;
  const int m0 = blockIdx.x * 64, n0 = blockIdx.y * 128;
  const int w = tid >> 6, lane = tid & 63, quad = lane >> 4, l16 = lane & 15;
  const int wm = (w & 1) * 32, wn = (w >> 1) * 64;
  const int srow = tid >> 2, scol = (tid & 3) * 8;
  const int K = C_SZ;
  f32x4 acc[2][4] = {};
  for (int k0 = 0; k0 < K; k0 += 32) {
    __syncthreads();
    const bf16* ga = A  + (size_t)(m0 + srow) * K + k0 + scol;
    const bf16* gb = Bw + (size_t)(n0 + srow) * K + k0 + scol;
    GLD_LDS16(ga,                 sA + tid * 8);
    GLD_LDS16(gb,                 sB + tid * 8);
    GLD_LDS16(gb + (size_t)64*K,  sB + tid * 8 + 2048);
    __syncthreads();
    bf16x8 af[2], bfr[4];
#pragma unroll
    for (int i = 0; i < 2; i++)
      af[i] = *(const bf16x8*)(sA + (wm + i*16 + l16) * 32 + quad * 8);
#pragma unroll
    for (int j = 0; j < 4; j++)
      bfr[j] = *(const bf16x8*)(sB + (wn + j*16 + l16) * 32 + quad * 8);
#pragma unroll
    for (int i = 0; i < 2; i++)
#pragma unroll
      for (int j = 0; j < 4; j++)
        acc[i][j] = mfma16(af[i], bfr[j], acc[i][j]);
  }
#pragma unroll
  for (int i = 0; i < 2; i++)
#pragma unroll
    for (int j = 0; j < 4; j++)
#pragma unroll
      for (int r = 0; r < 4; r++) {
        const int m = m0 + wm + i*16 + quad*4 + r;
        const int n = n0 + wn + j*16 + l16;
        dst[(size_t)m * C_SZ + n] = acc[i][j][r];
      }
}

// ---------------------------------------------------------------- flash attention (R6 config, measured-best)
// Flattened uniform schedule: per bh, 272 K-iters over 16 q-tiles (tile qi
// occupies g in [qi(qi+1), (qi+1)(qi+2))), split over 24 blocks of 11-12
// iters -> 768 identical blocks, 3/CU (LDS 52KB*3=156<=160), 12 waves/CU.
// Un-normalized partial (O bf16, l fp32) per touched tile; slot = p-p_first.
// NO min-waves launch bound: VGPR stays ~84, no spills (R9 lesson).
__device__ __forceinline__ int tile_of(int g) {
  int qi = (int)((sqrtf(4.f*(float)g + 1.f) - 1.f) * 0.5f);
  while ((qi + 1) * (qi + 2) <= g) ++qi;
  while (qi * (qi + 1) > g) --qi;
  return qi;
}

__global__ __launch_bounds__(256) void flash_attn(
    const bf16* __restrict__ qb, const bf16* __restrict__ kb,
    const bf16* __restrict__ vtb, bf16* __restrict__ Oa,
    float* __restrict__ lbuf) {
  __shared__ bf16 sK[2][64 * 64];
  __shared__ bf16 sVT[2][64 * 64];
  __shared__ bf16 sP[4][2560];   // per wave: 2 chunks of [32 rows][40]
  const int tid = threadIdx.x, w = tid >> 6, lane = tid & 63;
  const int quad = lane >> 4, l16 = lane & 15;
  const int bh = blockIdx.x & 31;          // idx%8 == bh%8 -> XCD affinity
  const int p  = blockIdx.x >> 5;          // 0..23
  const int gs = (34 * p) / 3, ge = (34 * (p + 1)) / 3;   // 272/24 schedule
  int qi = tile_of(gs);
  int tend = (qi + 1) * (qi + 2);
  int q0w = qi * 128 + w * 32;
  const bf16* Q  = qb  + (size_t)bh * T_SZ * HD;
  const bf16* Kp = kb  + (size_t)bh * T_SZ * HD;
  const bf16* Vt = vtb + (size_t)bh * HD * T_SZ;
  bf16x8 qf[2][2];
#pragma unroll
  for (int nt = 0; nt < 2; nt++)
#pragma unroll
    for (int ds = 0; ds < 2; ds++)
      qf[nt][ds] = *(const bf16x8*)(Q + (size_t)(q0w + nt*16 + l16) * HD + ds*32 + quad*8);
  float l_[2] = {0.f, 0.f};
  f32x4 ot[4][2] = {};
  bf16* sPw = &sP[w][0];
  const int srow = tid >> 3, scg = (tid & 7) ^ (srow & 7);

  // emit un-normalized partial (O rows bf16 + per-row l fp32) for tile qi
  auto partial_epilogue = [&]() {
    const int pf = (3 * qi * (qi + 1) + 2) / 34;     // first block of tile qi
    const int rec = (bh * 16 + qi) * 4 + (p - pf);
#pragma unroll
    for (int nt = 0; nt < 2; nt++) {
      float s = l_[nt];
      s += __shfl_xor(s, 16);
      s += __shfl_xor(s, 32);
      if (quad == 0) lbuf[rec * 128 + w*32 + nt*16 + l16] = s;
    }
#pragma unroll
    for (int dt = 0; dt < 4; dt++)
#pragma unroll
      for (int nt = 0; nt < 2; nt++) {
        union { bf16 h4[4]; unsigned long long ull; } pk;
#pragma unroll
        for (int r = 0; r < 4; r++) pk.h4[r] = (bf16)ot[dt][nt][r];
        *(unsigned long long*)(sPw + (nt*16 + l16)*72 + dt*16 + quad*4) = pk.ull;
      }
    asm volatile("" ::: "memory");
    const int oq = lane >> 1, hf = lane & 1;
    bf16* dst = Oa + (size_t)rec * 8192 + (w*32 + oq) * 64 + hf * 32;
#pragma unroll
    for (int j = 0; j < 4; j++)
      *(uint4*)(dst + j*8) = *(const uint4*)(sPw + oq*72 + hf*32 + j*8);
    asm volatile("" ::: "memory");
  };

  // stage first iter into buf[gs&1]
  {
    const int kt0 = (gs - qi * (qi + 1)) * 64;
    bf16* dK = sK[gs & 1];
    bf16* dV = sVT[gs & 1];
    GLD_LDS16(Kp + (size_t)(kt0 + srow) * HD + scg*8,        dK + tid*8);
    GLD_LDS16(Kp + (size_t)(kt0 + srow + 32) * HD + scg*8,   dK + tid*8 + 2048);
    GLD_LDS16(Vt + (size_t)srow * T_SZ + kt0 + scg*8,        dV + tid*8);
    GLD_LDS16(Vt + (size_t)(srow + 32) * T_SZ + kt0 + scg*8, dV + tid*8 + 2048);
  }

  for (int g = gs; g < ge; g++) {
    const int kt = (g - qi * (qi + 1)) * 64;
    __syncthreads();        // drains staging of buf[g&1]; fences prev compute
    if (g + 1 < ge) {       // prefetch next iter into the other buffer
      const int qn = (g + 1 >= tend) ? qi + 1 : qi;
      const int kn = (g + 1 - qn * (qn + 1)) * 64;
      bf16* dK = sK[(g + 1) & 1];
      bf16* dV = sVT[(g + 1) & 1];
      GLD_LDS16(Kp + (size_t)(kn + srow) * HD + scg*8,        dK + tid*8);
      GLD_LDS16(Kp + (size_t)(kn + srow + 32) * HD + scg*8,   dK + tid*8 + 2048);
      GLD_LDS16(Vt + (size_t)srow * T_SZ + kn + scg*8,        dV + tid*8);
      GLD_LDS16(Vt + (size_t)(srow + 32) * T_SZ + kn + scg*8, dV + tid*8 + 2048);
    }
    if (kt <= q0w + 31) {   // not fully masked for this wave
      const bf16* cK = sK[g & 1];
      const bf16* cV = sVT[g & 1];
      // ---- S^T = K.Q^T : st[mt][nt], m=k-pos, n=q-pos
      f32x4 st[4][2] = {};
#pragma unroll
      for (int mt = 0; mt < 4; mt++) {
#pragma unroll
        for (int ds = 0; ds < 2; ds++) {
          const int row = mt*16 + l16, cl = ds*4 + quad;
          const bf16x8 kf = *(const bf16x8*)(cK + row*64 + (cl ^ (row & 7)) * 8);
#pragma unroll
          for (int nt = 0; nt < 2; nt++)
            st[mt][nt] = mfma16(kf, qf[nt][ds], st[mt][nt]);
        }
      }
      // ---- causal mask (diagonal tiles only), exp2, pack P, partial sums
      if (kt + 63 > q0w) {
#pragma unroll
        for (int nt = 0; nt < 2; nt++) {
          const int qg = q0w + nt*16 + l16;
          const int kb0 = kt + quad*4;
#pragma unroll
          for (int mt = 0; mt < 4; mt++)
#pragma unroll
            for (int r = 0; r < 4; r++)
              st[mt][nt][r] = (kb0 + mt*16 + r <= qg) ? st[mt][nt][r] : -1e30f;
        }
      }
#pragma unroll
      for (int nt = 0; nt < 2; nt++) {
        float sum = 0.f;
#pragma unroll
        for (int mt = 0; mt < 4; mt++) {
          union { bf16 h4[4]; unsigned long long ull; } pk;
#pragma unroll
          for (int r = 0; r < 4; r++) {
            const float pv = __builtin_amdgcn_exp2f(st[mt][nt][r]);
            sum += pv;
            pk.h4[r] = (bf16)pv;
          }
          *(unsigned long long*)(sPw + (mt>>1)*1280 + (nt*16 + l16)*40 + (mt&1)*16 + quad*4) = pk.ull;
        }
        l_[nt] += sum;
      }
      asm volatile("" ::: "memory");   // wave-local: keep P writes before reads
      // ---- O^T += V^T . P  : m=d, n=q, k=t
      bf16x8 pfr[2][2];
#pragma unroll
      for (int nt = 0; nt < 2; nt++)
#pragma unroll
        for (int s = 0; s < 2; s++)
          pfr[nt][s] = *(const bf16x8*)(sPw + s*1280 + (nt*16 + l16)*40 + quad*8);
#pragma unroll
      for (int dt = 0; dt < 4; dt++) {
#pragma unroll
        for (int s = 0; s < 2; s++) {
          const int row = dt*16 + l16, cl = s*4 + quad;
          const bf16x8 vf = *(const bf16x8*)(cV + row*64 + (cl ^ (row & 7)) * 8);
#pragma unroll
          for (int nt = 0; nt < 2; nt++)
            ot[dt][nt] = mfma16(vf, pfr[nt][s], ot[dt][nt]);
        }
      }
    }
    if (g + 1 == tend || g + 1 == ge) {   // end of tile segment: emit partial
      partial_epilogue();
      if (g + 1 == tend && g + 1 < ge) {  // advance to next tile
        qi++; tend = (qi + 1) * (qi + 2); q0w = qi * 128 + w * 32;
#pragma unroll
        for (int nt = 0; nt < 2; nt++)
#pragma unroll
          for (int ds = 0; ds < 2; ds++)
            qf[nt][ds] = *(const bf16x8*)(Q + (size_t)(q0w + nt*16 + l16) * HD + ds*32 + quad*8);
        l_[0] = 0.f; l_[1] = 0.f;
#pragma unroll
        for (int dt = 0; dt < 4; dt++)
#pragma unroll
          for (int nt = 0; nt < 2; nt++)
            ot[dt][nt] = f32x4{0.f, 0.f, 0.f, 0.f};
      }
    }
  }
}

// ---------------------------------------------------------------- combine partials
__global__ __launch_bounds__(256) void combine_o(
    const bf16* __restrict__ Oa, const float* __restrict__ lbuf,
    bf16* __restrict__ ao) {
  const int inst = blockIdx.x;           // 512 = 16 qi x 32 bh
  const int bh = inst & 31, qi = inst >> 5;
  const int b = bh >> 3, h = bh & 7;
  const int g0 = qi * (qi + 1), geL = (qi + 1) * (qi + 2) - 1;
  const int pf = (3 * g0 + 2) / 34, pl = (3 * geL + 2) / 34;
  const int n = pl - pf + 1;             // contributors (1..4)
  const int base = (bh * 16 + qi) * 4;
  const int t = threadIdx.x;
  const int q = t >> 1, d0 = (t & 1) * 32;
  float l = 0.f;
  for (int s = 0; s < n; s++) l += lbuf[(base + s) * 128 + q];
  const float inv = 1.f / l;
  float acc[32] = {};
  for (int s = 0; s < n; s++) {
    const bf16* ps = Oa + ((size_t)(base + s)) * 8192 + q * 64 + d0;
#pragma unroll
    for (int c = 0; c < 4; c++) {
      union { uint4 u; bf16 h8[8]; } a;
      a.u = *(const uint4*)(ps + c*8);
#pragma unroll
      for (int j = 0; j < 8; j++) acc[c*8 + j] += (float)a.h8[j];
    }
  }
  const int tg = qi * 128 + q;
  bf16* dst = ao + ((size_t)(b*T_SZ + tg)) * C_SZ + h*HD + d0;
#pragma unroll
  for (int c = 0; c < 4; c++) {
    union { uint4 u; bf16 h8[8]; } o;
#pragma unroll
    for (int j = 0; j < 8; j++) o.h8[j] = (bf16)(acc[c*8 + j] * inv);
    *(uint4*)(dst + c*8) = o.u;
  }
}

// ---------------------------------------------------------------- launch
extern "C" void kernel_launch(void* const* d_in, const int* in_sizes, int n_in,
                              void* d_out, int out_size, void* d_ws, size_t ws_size,
                              hipStream_t stream) {
  const float* x    = (const float*)d_in[0];
  const float* cosp = (const float*)d_in[1];
  const float* sinp = (const float*)d_in[2];
  const float* wqkv = (const float*)d_in[3];
  const float* wout = (const float*)d_in[4];
  char* ws = (char*)d_ws;
  bf16* xb    = (bf16*)(ws);                 //  8,388,608
  bf16* wqkvb = (bf16*)(ws +  8388608);      //  1,572,864
  bf16* woutb = (bf16*)(ws +  9961472);      //    524,288
  bf16* qbuf  = (bf16*)(ws + 10485760);      //  8,388,608  (B,H,T,hd)
  bf16* kbuf  = (bf16*)(ws + 18874368);      //  8,388,608  (B,H,T,hd)
  bf16* vtbuf = (bf16*)(ws + 27262976);      //  8,388,608  (B,H,hd,T)
  bf16* ao    = (bf16*)(ws + 35651584);      //  8,388,608  (B,T,C)
  bf16* Oa    = (bf16*)(ws + 44040192);      // 33,554,432  2048 recs x 16 KB
  float* lbuf = (float*)(ws + 77594624);     //  1,048,576

  cvt_all<<<dim3(5120), dim3(256), 0, stream>>>(x, wqkv, wout, xb, wqkvb, woutb);
  gemm_qkv<<<dim3(64, 12), dim3(256), 0, stream>>>(
      xb, wqkvb, cosp, sinp, qbuf, kbuf, vtbuf);
  flash_attn<<<dim3(768), dim3(256), 0, stream>>>(qbuf, kbuf, vtbuf, Oa, lbuf);
  combine_o<<<dim3(512), dim3(256), 0, stream>>>(Oa, lbuf, ao);
  gemm_out<<<dim3(128, 4), dim3(256), 0, stream>>>(ao, woutb, (float*)d_out);
}